// Round 2
// baseline (410.003 us; speedup 1.0000x reference)
//
#include <hip/hip_runtime.h>
#include <hip/hip_bf16.h>

// Problem constants (B=1)
#define T_SEQ 2048
#define D_MODEL 2048
#define NH 16
#define HDIM 128
#define RD_ROT 64

typedef __bf16 bf16x8 __attribute__((ext_vector_type(8)));
typedef float f32x4 __attribute__((ext_vector_type(4)));

__device__ __forceinline__ void async_copy16(const __bf16* g, __bf16* l) {
    __builtin_amdgcn_global_load_lds(
        (const __attribute__((address_space(1))) void*)g,
        (__attribute__((address_space(3))) void*)l, 16, 0, 0);
}

// ---------------------------------------------------------------------------
// Cast fp32 -> bf16 for the 5 GEMM operands (hidden, Wq, Wk, Wv, Wo).
// Grid: dim3(2048, 5), 256 threads; each block converts one 2048-row.
// ---------------------------------------------------------------------------
__global__ __launch_bounds__(256) void cast_kernel(
    const float* __restrict__ s0, const float* __restrict__ s1, const float* __restrict__ s2,
    const float* __restrict__ s3, const float* __restrict__ s4,
    __bf16* __restrict__ d0, __bf16* __restrict__ d1, __bf16* __restrict__ d2,
    __bf16* __restrict__ d3, __bf16* __restrict__ d4)
{
    const float* s; __bf16* d;
    switch (blockIdx.y) {
        case 0: s = s0; d = d0; break;
        case 1: s = s1; d = d1; break;
        case 2: s = s2; d = d2; break;
        case 3: s = s3; d = d3; break;
        default: s = s4; d = d4; break;
    }
    size_t base = (size_t)blockIdx.x * D_MODEL + (size_t)threadIdx.x * 8;
    f32x4 a = *(const f32x4*)(s + base);
    f32x4 b = *(const f32x4*)(s + base + 4);
    bf16x8 o;
    #pragma unroll
    for (int i = 0; i < 4; i++) { o[i] = (__bf16)a[i]; o[i + 4] = (__bf16)b[i]; }
    *(bf16x8*)(d + base) = o;
}

// ---------------------------------------------------------------------------
// GEMM: C = A @ B^T.  A,B: 2048x2048 row-major bf16 (rows of B are K-vectors).
// blockIdx.z selects (B, C) so QKV runs as one launch. m97 structure:
// 128x128 tile, BK=32, 4 waves (2x2), 4x4 MFMA tiles/wave, plain LDS layout,
// global_load_lds width-16 staging. F32OUT selects fp32 epilogue (final GEMM).
// ---------------------------------------------------------------------------
template <bool F32OUT>
__global__ __launch_bounds__(256) void gemm_bt_kernel(
    const __bf16* __restrict__ A,
    const __bf16* __restrict__ B0, const __bf16* __restrict__ B1, const __bf16* __restrict__ B2,
    void* __restrict__ C0, void* __restrict__ C1, void* __restrict__ C2)
{
    constexpr int BM = 128, BK = 32, KD = D_MODEL;
    const __bf16* Bm = blockIdx.z == 0 ? B0 : (blockIdx.z == 1 ? B1 : B2);
    void* Cm         = blockIdx.z == 0 ? C0 : (blockIdx.z == 1 ? C1 : C2);

    __shared__ __align__(16) __bf16 As[BM * BK];
    __shared__ __align__(16) __bf16 Bs[BM * BK];

    const int lane = threadIdx.x & 63;
    const int wave = threadIdx.x >> 6;
    const int r15  = lane & 15;
    const int quad = lane >> 4;
    const int bm = blockIdx.x * BM;
    const int bn = blockIdx.y * BM;
    const int wm = (wave >> 1) * 64;
    const int wn = (wave & 1) * 64;

    f32x4 acc[4][4] = {};

    // staging: wave stages rows [wave*32, wave*32+32), 4 lanes x 8 elems per row
    const int srow = wave * 32 + (lane >> 2);
    const int sg   = lane & 3;

    for (int k0 = 0; k0 < KD; k0 += BK) {
        async_copy16(A  + (size_t)(bm + srow)      * KD + k0 + sg * 8, &As[wave * 1024]);
        async_copy16(A  + (size_t)(bm + srow + 16) * KD + k0 + sg * 8, &As[wave * 1024 + 512]);
        async_copy16(Bm + (size_t)(bn + srow)      * KD + k0 + sg * 8, &Bs[wave * 1024]);
        async_copy16(Bm + (size_t)(bn + srow + 16) * KD + k0 + sg * 8, &Bs[wave * 1024 + 512]);
        __syncthreads();

        bf16x8 av[4], bv[4];
        #pragma unroll
        for (int mt = 0; mt < 4; mt++)
            av[mt] = *(const bf16x8*)&As[(wm + mt * 16 + r15) * 32 + quad * 8];
        #pragma unroll
        for (int nt = 0; nt < 4; nt++)
            bv[nt] = *(const bf16x8*)&Bs[(wn + nt * 16 + r15) * 32 + quad * 8];
        #pragma unroll
        for (int mt = 0; mt < 4; mt++)
            #pragma unroll
            for (int nt = 0; nt < 4; nt++)
                acc[mt][nt] = __builtin_amdgcn_mfma_f32_16x16x32_bf16(av[mt], bv[nt], acc[mt][nt], 0, 0, 0);
        __syncthreads();
    }

    // epilogue: C/D layout row = quad*4 + r, col = lane&15
    #pragma unroll
    for (int mt = 0; mt < 4; mt++) {
        #pragma unroll
        for (int r = 0; r < 4; r++) {
            size_t row = bm + wm + mt * 16 + quad * 4 + r;
            #pragma unroll
            for (int nt = 0; nt < 4; nt++) {
                size_t col = bn + wn + nt * 16 + r15;
                if (F32OUT) ((float*)Cm)[row * D_MODEL + col] = acc[mt][nt][r];
                else      ((__bf16*)Cm)[row * D_MODEL + col] = (__bf16)acc[mt][nt][r];
            }
        }
    }
}

// ---------------------------------------------------------------------------
// Preproc: causal conv(K=4) + SiLU (+ RMSNorm + RoPE for q,k).
// One block = one (t, head, which), 128 threads (one per channel in head).
// Raw q/k/v are bf16 (GEMM output); cos/sin/conv/norm weights are fp32 d_in.
// q,k written (H, T, HD); v written transposed (H, HD, T).
// ---------------------------------------------------------------------------
__global__ __launch_bounds__(128) void preproc_kernel(
    const __bf16* __restrict__ q_raw, const __bf16* __restrict__ k_raw, const __bf16* __restrict__ v_raw,
    const float* __restrict__ cwq, const float* __restrict__ cwk, const float* __restrict__ cwv,
    const float* __restrict__ qnw, const float* __restrict__ knw,
    const float* __restrict__ cosb, const float* __restrict__ sinb,
    __bf16* __restrict__ q_proc, __bf16* __restrict__ k_proc, __bf16* __restrict__ v_t)
{
    const int t = blockIdx.x;
    const int h = blockIdx.y;
    const int which = blockIdx.z;
    const int dl = threadIdx.x;
    const int d = h * HDIM + dl;

    const __bf16* X = which == 0 ? q_raw : (which == 1 ? k_raw : v_raw);
    const float*  W = which == 0 ? cwq : (which == 1 ? cwk : cwv);

    float y = 0.f;
    #pragma unroll
    for (int j = 0; j < 4; j++) {
        int tt = t + j - 3;
        if (tt >= 0) y += (float)X[(size_t)tt * D_MODEL + d] * W[d * 4 + j];
    }
    float sil = y / (1.f + __expf(-y));   // silu

    if (which == 2) {  // v: no norm / rope, store transposed
        v_t[((size_t)h * HDIM + dl) * T_SEQ + t] = (__bf16)sil;
        return;
    }

    // RMS norm over the 128 channels of this head
    float ss = sil * sil;
    #pragma unroll
    for (int off = 32; off > 0; off >>= 1) ss += __shfl_down(ss, off);
    __shared__ float wsum[2];
    __shared__ float vals[HDIM];
    if ((threadIdx.x & 63) == 0) wsum[threadIdx.x >> 6] = ss;
    __syncthreads();
    float mean = (wsum[0] + wsum[1]) * (1.f / 128.f);
    float inv = rsqrtf(mean + 1e-5f);
    const float* nw = which == 0 ? qnw : knw;
    float yn = sil * inv * nw[dl];
    vals[dl] = yn;
    __syncthreads();

    float outv;
    if (dl < RD_ROT) {
        float c = cosb[t * RD_ROT + dl];
        float s = sinb[t * RD_ROT + dl];
        float rot = (dl < 32) ? -vals[dl + 32] : vals[dl - 32];  // rotate_half
        outv = -(yn * c + rot * s);                              // reference negates x_rot
    } else {
        outv = yn;
    }
    __bf16* P = which == 0 ? q_proc : k_proc;
    P[((size_t)h * T_SEQ + t) * HDIM + dl] = (__bf16)outv;
}

// ---------------------------------------------------------------------------
// Flash attention, causal. One block = (64-row Q tile, head). 4 waves; wave w
// owns q rows [w*16, w*16+16) (Q frags in registers). K staged (t, hd), V
// staged transposed (hd, t). Online softmax in fp32; P round-trips through
// LDS (C-layout write -> A-layout read).
// ---------------------------------------------------------------------------
__global__ __launch_bounds__(256) void attn_kernel(
    const __bf16* __restrict__ Qp,   // (H, T, HD)
    const __bf16* __restrict__ Kp,   // (H, T, HD)
    const __bf16* __restrict__ Vt,   // (H, HD, T)
    __bf16* __restrict__ Op)         // (T, H*HD)
{
    constexpr int TQ = 64, TK = 64;
    __shared__ __align__(16) __bf16 Ks[TK * HDIM];   // rows = t, plain layout
    __shared__ __align__(16) __bf16 Vs[HDIM * TK];   // rows = hd
    __shared__ __align__(16) __bf16 Ps[TQ * TK];     // rows = q

    const int lane = threadIdx.x & 63;
    const int wave = threadIdx.x >> 6;
    const int r15  = lane & 15;
    const int quad = lane >> 4;
    const int h = blockIdx.y;
    // balance causal load across CUs: reverse tile order for half the heads
    const int qi = (blockIdx.y & 8) ? ((int)gridDim.x - 1 - (int)blockIdx.x) : (int)blockIdx.x;
    const int q0 = qi * TQ;

    // Q fragments (A layout: m = lane&15, k = quad*8+j within each 32-k tile)
    bf16x8 qf[4];
    const __bf16* qbase = Qp + ((size_t)h * T_SEQ + q0 + wave * 16 + r15) * HDIM;
    #pragma unroll
    for (int s = 0; s < 4; s++) qf[s] = *(const bf16x8*)(qbase + s * 32 + quad * 8);

    f32x4 oacc[8] = {};
    float mrow[4], lrow[4];
    #pragma unroll
    for (int r = 0; r < 4; r++) { mrow[r] = -1e30f; lrow[r] = 0.f; }
    const float scale = 0.08838834764831845f;  // 1/sqrt(128)

    const int ntk = q0 / TK + 1;
    for (int it = 0; it < ntk; it++) {
        const int tk0 = it * TK;
        // ---- stage K (64x128) and V^T (128x64) tiles ----
        #pragma unroll
        for (int i = 0; i < 4; i++) {
            int chunk = wave * 4 + i;
            int krow = chunk * 4 + (lane >> 4);
            async_copy16(Kp + ((size_t)h * T_SEQ + tk0 + krow) * HDIM + r15 * 8, &Ks[chunk * 512]);
            int vrow = chunk * 8 + (lane >> 3);
            async_copy16(Vt + ((size_t)h * HDIM + vrow) * T_SEQ + tk0 + (lane & 7) * 8, &Vs[chunk * 512]);
        }
        __syncthreads();

        // ---- S = Q K^T (per wave: 16 x 64) ----
        f32x4 sacc[4] = {};
        #pragma unroll
        for (int s = 0; s < 4; s++) {
            #pragma unroll
            for (int nt = 0; nt < 4; nt++) {
                bf16x8 kf = *(const bf16x8*)&Ks[(nt * 16 + r15) * HDIM + (s * 4 + quad) * 8];
                sacc[nt] = __builtin_amdgcn_mfma_f32_16x16x32_bf16(qf[s], kf, sacc[nt], 0, 0, 0);
            }
        }

        // ---- mask + scale + online softmax (rows quad*4+r, cols r15-lanes) ----
        float sv[4][4], tmax[4];
        #pragma unroll
        for (int r = 0; r < 4; r++) tmax[r] = -1e30f;
        #pragma unroll
        for (int nt = 0; nt < 4; nt++) {
            #pragma unroll
            for (int r = 0; r < 4; r++) {
                int qrow = q0 + wave * 16 + quad * 4 + r;
                int kcol = tk0 + nt * 16 + r15;
                float x = sacc[nt][r] * scale;
                x = (kcol > qrow) ? -1e30f : x;
                sv[nt][r] = x;
                tmax[r] = fmaxf(tmax[r], x);
            }
        }
        #pragma unroll
        for (int r = 0; r < 4; r++) {
            #pragma unroll
            for (int off = 1; off < 16; off <<= 1)
                tmax[r] = fmaxf(tmax[r], __shfl_xor(tmax[r], off));
        }
        float alpha[4], rsum[4];
        #pragma unroll
        for (int r = 0; r < 4; r++) {
            float mn = fmaxf(mrow[r], tmax[r]);
            alpha[r] = __expf(mrow[r] - mn);
            mrow[r] = mn;
            rsum[r] = 0.f;
        }
        float pv[4][4];
        #pragma unroll
        for (int nt = 0; nt < 4; nt++) {
            #pragma unroll
            for (int r = 0; r < 4; r++) {
                float p = __expf(sv[nt][r] - mrow[r]);
                pv[nt][r] = p;
                rsum[r] += p;
            }
        }
        #pragma unroll
        for (int r = 0; r < 4; r++) {
            #pragma unroll
            for (int off = 1; off < 16; off <<= 1) rsum[r] += __shfl_xor(rsum[r], off);
            lrow[r] = lrow[r] * alpha[r] + rsum[r];
        }
        #pragma unroll
        for (int nt = 0; nt < 8; nt++) {
            #pragma unroll
            for (int r = 0; r < 4; r++) oacc[nt][r] *= alpha[r];
        }

        // ---- P: C-layout -> LDS -> A-layout (same-wave region, in-order DS) ----
        #pragma unroll
        for (int nt = 0; nt < 4; nt++) {
            #pragma unroll
            for (int r = 0; r < 4; r++)
                Ps[(wave * 16 + quad * 4 + r) * TK + nt * 16 + r15] = (__bf16)pv[nt][r];
        }

        // ---- O += P V ----
        #pragma unroll
        for (int s = 0; s < 2; s++) {
            bf16x8 pf = *(const bf16x8*)&Ps[(wave * 16 + r15) * TK + (s * 4 + quad) * 8];
            #pragma unroll
            for (int nt = 0; nt < 8; nt++) {
                bf16x8 vf = *(const bf16x8*)&Vs[(nt * 16 + r15) * TK + (s * 4 + quad) * 8];
                oacc[nt] = __builtin_amdgcn_mfma_f32_16x16x32_bf16(pf, vf, oacc[nt], 0, 0, 0);
            }
        }
        __syncthreads();
    }

    // ---- epilogue: O / l, write (T, H*HD) bf16 ----
    #pragma unroll
    for (int r = 0; r < 4; r++) {
        float inv = 1.0f / lrow[r];
        size_t row = q0 + wave * 16 + quad * 4 + r;
        #pragma unroll
        for (int nt = 0; nt < 8; nt++)
            Op[row * D_MODEL + h * HDIM + nt * 16 + r15] = (__bf16)(oacc[nt][r] * inv);
    }
}

// ---------------------------------------------------------------------------
extern "C" void kernel_launch(void* const* d_in, const int* in_sizes, int n_in,
                              void* d_out, int out_size, void* d_ws, size_t ws_size,
                              hipStream_t stream) {
    (void)in_sizes; (void)n_in; (void)out_size; (void)ws_size;
    const float* hidden = (const float*)d_in[0];
    const float* cosb   = (const float*)d_in[1];
    const float* sinb   = (const float*)d_in[2];
    const float* Wq     = (const float*)d_in[3];
    const float* Wk     = (const float*)d_in[4];
    const float* Wv     = (const float*)d_in[5];
    const float* Wo     = (const float*)d_in[6];
    const float* cwq    = (const float*)d_in[7];
    const float* cwk    = (const float*)d_in[8];
    const float* cwv    = (const float*)d_in[9];
    const float* qnw    = (const float*)d_in[10];
    const float* knw    = (const float*)d_in[11];

    const size_t NEL = (size_t)T_SEQ * D_MODEL;  // 4M elements
    __bf16* ws = (__bf16*)d_ws;
    __bf16* h_bf   = ws + 0 * NEL;   // later reused as attn_b
    __bf16* Wq_bf  = ws + 1 * NEL;   // later reused as q_proc
    __bf16* Wk_bf  = ws + 2 * NEL;   // later reused as k_proc
    __bf16* Wv_bf  = ws + 3 * NEL;   // later reused as v_t
    __bf16* Wo_bf  = ws + 4 * NEL;   // persists to final GEMM
    __bf16* q_raw  = ws + 5 * NEL;
    __bf16* k_raw  = ws + 6 * NEL;
    __bf16* v_raw  = ws + 7 * NEL;
    __bf16* q_proc = Wq_bf;
    __bf16* k_proc = Wk_bf;
    __bf16* v_t    = Wv_bf;
    __bf16* attn_b = h_bf;
    float*  out    = (float*)d_out;

    // 0. cast fp32 inputs to bf16 (hidden + 4 weight matrices)
    cast_kernel<<<dim3(T_SEQ, 5), 256, 0, stream>>>(hidden, Wq, Wk, Wv, Wo,
                                                    h_bf, Wq_bf, Wk_bf, Wv_bf, Wo_bf);
    // 1. q,k,v = hidden @ {Wq,Wk,Wv}^T  (one batched launch, bf16 out)
    gemm_bt_kernel<false><<<dim3(16, 16, 3), 256, 0, stream>>>(
        h_bf, Wq_bf, Wk_bf, Wv_bf, q_raw, k_raw, v_raw);
    // 2. conv + silu (+ norm + rope); layout shuffle for attention
    preproc_kernel<<<dim3(T_SEQ, NH, 3), 128, 0, stream>>>(
        q_raw, k_raw, v_raw, cwq, cwk, cwv, qnw, knw, cosb, sinb, q_proc, k_proc, v_t);
    // 3. causal flash attention
    attn_kernel<<<dim3(T_SEQ / 64, NH), 256, 0, stream>>>(q_proc, k_proc, v_t, attn_b);
    // 4. out = attn @ Wo^T  (fp32 out)
    gemm_bt_kernel<true><<<dim3(16, 16, 1), 256, 0, stream>>>(
        attn_b, Wo_bf, Wo_bf, Wo_bf, out, out, out);
}

// Round 3
// 348.451 us; speedup vs baseline: 1.1766x; 1.1766x over previous
//
#include <hip/hip_runtime.h>
#include <hip/hip_bf16.h>

// Problem constants (B=1)
#define T_SEQ 2048
#define D_MODEL 2048
#define NH 16
#define HDIM 128
#define RD_ROT 64

typedef __bf16 bf16x8 __attribute__((ext_vector_type(8)));
typedef float f32x4 __attribute__((ext_vector_type(4)));

__device__ __forceinline__ void async_copy16(const __bf16* g, __bf16* l) {
    __builtin_amdgcn_global_load_lds(
        (const __attribute__((address_space(1))) void*)g,
        (__attribute__((address_space(3))) void*)l, 16, 0, 0);
}

// ---------------------------------------------------------------------------
// Cast fp32 -> bf16 for the 5 GEMM operands (hidden, Wq, Wk, Wv, Wo).
// ---------------------------------------------------------------------------
__global__ __launch_bounds__(256) void cast_kernel(
    const float* __restrict__ s0, const float* __restrict__ s1, const float* __restrict__ s2,
    const float* __restrict__ s3, const float* __restrict__ s4,
    __bf16* __restrict__ d0, __bf16* __restrict__ d1, __bf16* __restrict__ d2,
    __bf16* __restrict__ d3, __bf16* __restrict__ d4)
{
    const float* s; __bf16* d;
    switch (blockIdx.y) {
        case 0: s = s0; d = d0; break;
        case 1: s = s1; d = d1; break;
        case 2: s = s2; d = d2; break;
        case 3: s = s3; d = d3; break;
        default: s = s4; d = d4; break;
    }
    size_t base = (size_t)blockIdx.x * D_MODEL + (size_t)threadIdx.x * 8;
    f32x4 a = *(const f32x4*)(s + base);
    f32x4 b = *(const f32x4*)(s + base + 4);
    bf16x8 o;
    #pragma unroll
    for (int i = 0; i < 4; i++) { o[i] = (__bf16)a[i]; o[i + 4] = (__bf16)b[i]; }
    *(bf16x8*)(d + base) = o;
}

// ---------------------------------------------------------------------------
// GEMM: C = A @ B^T, 128x128 tile, BK=32, LDS XOR-swizzled (group ^ (row&3)):
// swizzle applied on the GLOBAL source group so global_load_lds's
// lane-contiguous LDS destination stays valid. Reads are bank-ideal.
// blockIdx.z selects (B, C) so QKV runs as one launch.
// ---------------------------------------------------------------------------
__global__ __launch_bounds__(256) void gemm_bt_kernel(
    const __bf16* __restrict__ A,
    const __bf16* __restrict__ B0, const __bf16* __restrict__ B1, const __bf16* __restrict__ B2,
    __bf16* __restrict__ C0, __bf16* __restrict__ C1, __bf16* __restrict__ C2)
{
    constexpr int BM = 128, BK = 32, KD = D_MODEL;
    const __bf16* Bm = blockIdx.z == 0 ? B0 : (blockIdx.z == 1 ? B1 : B2);
    __bf16* Cm       = blockIdx.z == 0 ? C0 : (blockIdx.z == 1 ? C1 : C2);

    __shared__ __align__(16) __bf16 As[BM * BK];
    __shared__ __align__(16) __bf16 Bs[BM * BK];

    const int lane = threadIdx.x & 63;
    const int wave = threadIdx.x >> 6;
    const int r15  = lane & 15;
    const int quad = lane >> 4;
    const int bm = blockIdx.x * BM;
    const int bn = blockIdx.y * BM;
    const int wm = (wave >> 1) * 64;
    const int wn = (wave & 1) * 64;

    f32x4 acc[4][4] = {};

    // staging: lane l -> local row l>>2, LDS group l&3; source group swizzled
    const int srow = wave * 32 + (lane >> 2);
    const int sg   = (lane & 3) ^ ((lane >> 2) & 3);   // g_glob = g_lds ^ (row&3)

    for (int k0 = 0; k0 < KD; k0 += BK) {
        async_copy16(A  + (size_t)(bm + srow)      * KD + k0 + sg * 8, &As[wave * 1024]);
        async_copy16(A  + (size_t)(bm + srow + 16) * KD + k0 + sg * 8, &As[wave * 1024 + 512]);
        async_copy16(Bm + (size_t)(bn + srow)      * KD + k0 + sg * 8, &Bs[wave * 1024]);
        async_copy16(Bm + (size_t)(bn + srow + 16) * KD + k0 + sg * 8, &Bs[wave * 1024 + 512]);
        __syncthreads();

        bf16x8 av[4], bv[4];
        #pragma unroll
        for (int mt = 0; mt < 4; mt++)
            av[mt] = *(const bf16x8*)&As[(wm + mt * 16 + r15) * 32 + ((quad ^ (r15 & 3)) << 3)];
        #pragma unroll
        for (int nt = 0; nt < 4; nt++)
            bv[nt] = *(const bf16x8*)&Bs[(wn + nt * 16 + r15) * 32 + ((quad ^ (r15 & 3)) << 3)];
        #pragma unroll
        for (int mt = 0; mt < 4; mt++)
            #pragma unroll
            for (int nt = 0; nt < 4; nt++)
                acc[mt][nt] = __builtin_amdgcn_mfma_f32_16x16x32_bf16(av[mt], bv[nt], acc[mt][nt], 0, 0, 0);
        __syncthreads();
    }

    #pragma unroll
    for (int mt = 0; mt < 4; mt++) {
        #pragma unroll
        for (int r = 0; r < 4; r++) {
            size_t row = bm + wm + mt * 16 + quad * 4 + r;
            #pragma unroll
            for (int nt = 0; nt < 4; nt++) {
                size_t col = bn + wn + nt * 16 + r15;
                Cm[row * D_MODEL + col] = (__bf16)acc[mt][nt][r];
            }
        }
    }
}

// ---------------------------------------------------------------------------
// Split-K GEMM for the final projection (fp32 atomic epilogue, d_out zeroed
// by hipMemsetAsync). Grid (16,16,2): z = K half. Fixes 1-block/CU droop.
// ---------------------------------------------------------------------------
__global__ __launch_bounds__(256) void gemm_bt_splitk_kernel(
    const __bf16* __restrict__ A, const __bf16* __restrict__ Bm, float* __restrict__ C)
{
    constexpr int BM = 128, BK = 32, KD = D_MODEL;
    __shared__ __align__(16) __bf16 As[BM * BK];
    __shared__ __align__(16) __bf16 Bs[BM * BK];

    const int lane = threadIdx.x & 63;
    const int wave = threadIdx.x >> 6;
    const int r15  = lane & 15;
    const int quad = lane >> 4;
    const int bm = blockIdx.x * BM;
    const int bn = blockIdx.y * BM;
    const int wm = (wave >> 1) * 64;
    const int wn = (wave & 1) * 64;
    const int kbase = blockIdx.z * (KD / 2);

    f32x4 acc[4][4] = {};
    const int srow = wave * 32 + (lane >> 2);
    const int sg   = (lane & 3) ^ ((lane >> 2) & 3);

    for (int k0 = kbase; k0 < kbase + KD / 2; k0 += BK) {
        async_copy16(A  + (size_t)(bm + srow)      * KD + k0 + sg * 8, &As[wave * 1024]);
        async_copy16(A  + (size_t)(bm + srow + 16) * KD + k0 + sg * 8, &As[wave * 1024 + 512]);
        async_copy16(Bm + (size_t)(bn + srow)      * KD + k0 + sg * 8, &Bs[wave * 1024]);
        async_copy16(Bm + (size_t)(bn + srow + 16) * KD + k0 + sg * 8, &Bs[wave * 1024 + 512]);
        __syncthreads();

        bf16x8 av[4], bv[4];
        #pragma unroll
        for (int mt = 0; mt < 4; mt++)
            av[mt] = *(const bf16x8*)&As[(wm + mt * 16 + r15) * 32 + ((quad ^ (r15 & 3)) << 3)];
        #pragma unroll
        for (int nt = 0; nt < 4; nt++)
            bv[nt] = *(const bf16x8*)&Bs[(wn + nt * 16 + r15) * 32 + ((quad ^ (r15 & 3)) << 3)];
        #pragma unroll
        for (int mt = 0; mt < 4; mt++)
            #pragma unroll
            for (int nt = 0; nt < 4; nt++)
                acc[mt][nt] = __builtin_amdgcn_mfma_f32_16x16x32_bf16(av[mt], bv[nt], acc[mt][nt], 0, 0, 0);
        __syncthreads();
    }

    #pragma unroll
    for (int mt = 0; mt < 4; mt++) {
        #pragma unroll
        for (int r = 0; r < 4; r++) {
            size_t row = bm + wm + mt * 16 + quad * 4 + r;
            #pragma unroll
            for (int nt = 0; nt < 4; nt++) {
                size_t col = bn + wn + nt * 16 + r15;
                atomicAdd(&C[row * D_MODEL + col], acc[mt][nt][r]);
            }
        }
    }
}

// ---------------------------------------------------------------------------
// Preproc q/k: conv(K=4)+SiLU+RMSNorm+RoPE, pure-register (no LDS).
// Block = (t, which in {q,k}), 256 threads; thread -> 8 channels; head = 16
// threads; RMS reduce + RoPE partner exchange via intra-wave shuffles.
// ---------------------------------------------------------------------------
__global__ __launch_bounds__(256) void preproc_qk_kernel(
    const __bf16* __restrict__ q_raw, const __bf16* __restrict__ k_raw,
    const float* __restrict__ cwq, const float* __restrict__ cwk,
    const float* __restrict__ qnw, const float* __restrict__ knw,
    const float* __restrict__ cosb, const float* __restrict__ sinb,
    __bf16* __restrict__ q_proc, __bf16* __restrict__ k_proc)
{
    const int t = blockIdx.x;
    const int which = blockIdx.y;
    const __bf16* X = which ? k_raw : q_raw;
    const float*  W = which ? cwk : cwq;
    const float*  nw = which ? knw : qnw;
    __bf16* P = which ? k_proc : q_proc;

    const int tid = threadIdx.x;
    const int c0  = tid * 8;           // global channel base
    const int h   = tid >> 4;
    const int dl0 = (tid & 15) * 8;    // head-local channel base

    f32x4 wv[8];
    #pragma unroll
    for (int i = 0; i < 8; i++) wv[i] = *(const f32x4*)&W[(c0 + i) * 4];

    float acc[8] = {};
    #pragma unroll
    for (int j = 0; j < 4; j++) {
        int tt = t + j - 3;
        if (tt >= 0) {
            bf16x8 xv = *(const bf16x8*)&X[(size_t)tt * D_MODEL + c0];
            #pragma unroll
            for (int i = 0; i < 8; i++) acc[i] += (float)xv[i] * wv[i][j];
        }
    }
    float sil[8], ss = 0.f;
    #pragma unroll
    for (int i = 0; i < 8; i++) {
        float s = acc[i] / (1.f + __expf(-acc[i]));
        sil[i] = s; ss += s * s;
    }
    #pragma unroll
    for (int off = 1; off < 16; off <<= 1) ss += __shfl_xor(ss, off);
    float inv = rsqrtf(ss * (1.f / 128.f) + 1e-5f);

    f32x4 nv0 = *(const f32x4*)&nw[dl0];
    f32x4 nv1 = *(const f32x4*)&nw[dl0 + 4];
    float yn[8];
    #pragma unroll
    for (int i = 0; i < 8; i++) yn[i] = sil[i] * inv * (i < 4 ? nv0[i] : nv1[i - 4]);

    float partner[8];
    #pragma unroll
    for (int i = 0; i < 8; i++) partner[i] = __shfl_xor(yn[i], 4);  // dl ^ 32

    bf16x8 o;
    if (dl0 < RD_ROT) {
        f32x4 cv0 = *(const f32x4*)&cosb[t * RD_ROT + dl0];
        f32x4 cv1 = *(const f32x4*)&cosb[t * RD_ROT + dl0 + 4];
        f32x4 sv0 = *(const f32x4*)&sinb[t * RD_ROT + dl0];
        f32x4 sv1 = *(const f32x4*)&sinb[t * RD_ROT + dl0 + 4];
        #pragma unroll
        for (int i = 0; i < 8; i++) {
            int dl = dl0 + i;
            float c = i < 4 ? cv0[i] : cv1[i - 4];
            float s = i < 4 ? sv0[i] : sv1[i - 4];
            float rot = (dl < 32) ? -partner[i] : partner[i];  // rotate_half
            o[i] = (__bf16)(-(yn[i] * c + rot * s));           // reference negates x_rot
        }
    } else {
        #pragma unroll
        for (int i = 0; i < 8; i++) o[i] = (__bf16)yn[i];
    }
    *(bf16x8*)&P[((size_t)h * T_SEQ + t) * HDIM + dl0] = o;
}

// ---------------------------------------------------------------------------
// Preproc v: conv+SiLU, 8 t-steps per thread so the transposed (H,HD,T) store
// is one contiguous bf16x8 per thread. Grid (T/8, H), 128 threads (channel).
// ---------------------------------------------------------------------------
__global__ __launch_bounds__(128) void preproc_v_kernel(
    const __bf16* __restrict__ v_raw, const float* __restrict__ cwv,
    __bf16* __restrict__ v_t)
{
    const int t0 = blockIdx.x * 8;
    const int h = blockIdx.y;
    const int dl = threadIdx.x;
    const int d = h * HDIM + dl;

    f32x4 wv = *(const f32x4*)&cwv[d * 4];
    float x[11];
    #pragma unroll
    for (int m = 0; m < 11; m++) {
        int tt = t0 - 3 + m;
        x[m] = (tt >= 0) ? (float)v_raw[(size_t)tt * D_MODEL + d] : 0.f;
    }
    bf16x8 o;
    #pragma unroll
    for (int r = 0; r < 8; r++) {
        float y = x[r] * wv[0] + x[r + 1] * wv[1] + x[r + 2] * wv[2] + x[r + 3] * wv[3];
        o[r] = (__bf16)(y / (1.f + __expf(-y)));
    }
    *(bf16x8*)&v_t[((size_t)h * HDIM + dl) * T_SEQ + t0] = o;
}

// ---------------------------------------------------------------------------
// Flash attention, causal, LDS XOR-swizzled (fixes 16-way conflicts).
// Swizzle rule everywhere: LDS slot g holds global group g ^ (row & mask);
// staging permutes the global source group, reads use slot = G ^ (row&mask).
// ---------------------------------------------------------------------------
__global__ __launch_bounds__(256) void attn_kernel(
    const __bf16* __restrict__ Qp,   // (H, T, HD)
    const __bf16* __restrict__ Kp,   // (H, T, HD)
    const __bf16* __restrict__ Vt,   // (H, HD, T)
    __bf16* __restrict__ Op)         // (T, H*HD)
{
    constexpr int TQ = 64, TK = 64;
    __shared__ __align__(16) __bf16 Ks[TK * HDIM];   // rows=t, 16 groups, mask 15
    __shared__ __align__(16) __bf16 Vs[HDIM * TK];   // rows=hd, 8 groups, mask 7
    __shared__ __align__(16) __bf16 Ps[TQ * TK];     // rows=q,  8 groups, mask 7

    const int lane = threadIdx.x & 63;
    const int wave = threadIdx.x >> 6;
    const int r15  = lane & 15;
    const int quad = lane >> 4;
    const int h = blockIdx.y;
    // pairing: block b and b+256 (round-robin same CU) get work (x+1)+(32-x)=33
    const int qi = (blockIdx.y & 8) ? ((int)gridDim.x - 1 - (int)blockIdx.x) : (int)blockIdx.x;
    const int q0 = qi * TQ;

    bf16x8 qf[4];
    const __bf16* qbase = Qp + ((size_t)h * T_SEQ + q0 + wave * 16 + r15) * HDIM;
    #pragma unroll
    for (int s = 0; s < 4; s++) qf[s] = *(const bf16x8*)(qbase + s * 32 + quad * 8);

    f32x4 oacc[8] = {};
    float mrow[4], lrow[4];
    #pragma unroll
    for (int r = 0; r < 4; r++) { mrow[r] = -1e30f; lrow[r] = 0.f; }
    const float scale = 0.08838834764831845f;  // 1/sqrt(128)

    const int ntk = q0 / TK + 1;
    for (int it = 0; it < ntk; it++) {
        const int tk0 = it * TK;
        #pragma unroll
        for (int i = 0; i < 4; i++) {
            int chunk = wave * 4 + i;
            int krow = chunk * 4 + (lane >> 4);
            int kg = (lane & 15) ^ (krow & 15);
            async_copy16(Kp + ((size_t)h * T_SEQ + tk0 + krow) * HDIM + kg * 8, &Ks[chunk * 512]);
            int vrow = chunk * 8 + (lane >> 3);
            int vg = (lane & 7) ^ (vrow & 7);
            async_copy16(Vt + ((size_t)h * HDIM + vrow) * T_SEQ + tk0 + vg * 8, &Vs[chunk * 512]);
        }
        __syncthreads();

        // ---- S = Q K^T ----
        f32x4 sacc[4] = {};
        #pragma unroll
        for (int s = 0; s < 4; s++) {
            #pragma unroll
            for (int nt = 0; nt < 4; nt++) {
                bf16x8 kf = *(const bf16x8*)&Ks[(nt * 16 + r15) * HDIM + (((s * 4 + quad) ^ r15) << 3)];
                sacc[nt] = __builtin_amdgcn_mfma_f32_16x16x32_bf16(qf[s], kf, sacc[nt], 0, 0, 0);
            }
        }

        // ---- mask + scale + online softmax ----
        float sv[4][4], tmax[4];
        #pragma unroll
        for (int r = 0; r < 4; r++) tmax[r] = -1e30f;
        #pragma unroll
        for (int nt = 0; nt < 4; nt++) {
            #pragma unroll
            for (int r = 0; r < 4; r++) {
                int qrow = q0 + wave * 16 + quad * 4 + r;
                int kcol = tk0 + nt * 16 + r15;
                float x = sacc[nt][r] * scale;
                x = (kcol > qrow) ? -1e30f : x;
                sv[nt][r] = x;
                tmax[r] = fmaxf(tmax[r], x);
            }
        }
        #pragma unroll
        for (int r = 0; r < 4; r++) {
            #pragma unroll
            for (int off = 1; off < 16; off <<= 1)
                tmax[r] = fmaxf(tmax[r], __shfl_xor(tmax[r], off));
        }
        float alpha[4], rsum[4];
        #pragma unroll
        for (int r = 0; r < 4; r++) {
            float mn = fmaxf(mrow[r], tmax[r]);
            alpha[r] = __expf(mrow[r] - mn);
            mrow[r] = mn;
            rsum[r] = 0.f;
        }
        float pv[4][4];
        #pragma unroll
        for (int nt = 0; nt < 4; nt++) {
            #pragma unroll
            for (int r = 0; r < 4; r++) {
                float p = __expf(sv[nt][r] - mrow[r]);
                pv[nt][r] = p;
                rsum[r] += p;
            }
        }
        #pragma unroll
        for (int r = 0; r < 4; r++) {
            #pragma unroll
            for (int off = 1; off < 16; off <<= 1) rsum[r] += __shfl_xor(rsum[r], off);
            lrow[r] = lrow[r] * alpha[r] + rsum[r];
        }
        #pragma unroll
        for (int nt = 0; nt < 8; nt++) {
            #pragma unroll
            for (int r = 0; r < 4; r++) oacc[nt][r] *= alpha[r];
        }

        // ---- P: C-layout -> LDS (swizzled) -> A-layout ----
        #pragma unroll
        for (int nt = 0; nt < 4; nt++) {
            #pragma unroll
            for (int r = 0; r < 4; r++) {
                int prow = wave * 16 + quad * 4 + r;
                int pcol = nt * 16 + r15;
                Ps[prow * TK + ((((pcol >> 3) ^ (prow & 7)) << 3) | (pcol & 7))] = (__bf16)pv[nt][r];
            }
        }

        // ---- O += P V ----
        #pragma unroll
        for (int s = 0; s < 2; s++) {
            bf16x8 pf = *(const bf16x8*)&Ps[(wave * 16 + r15) * TK + (((s * 4 + quad) ^ (r15 & 7)) << 3)];
            #pragma unroll
            for (int nt = 0; nt < 8; nt++) {
                bf16x8 vf = *(const bf16x8*)&Vs[(nt * 16 + r15) * TK + (((s * 4 + quad) ^ (r15 & 7)) << 3)];
                oacc[nt] = __builtin_amdgcn_mfma_f32_16x16x32_bf16(pf, vf, oacc[nt], 0, 0, 0);
            }
        }
        __syncthreads();
    }

    #pragma unroll
    for (int r = 0; r < 4; r++) {
        float inv = 1.0f / lrow[r];
        size_t row = q0 + wave * 16 + quad * 4 + r;
        #pragma unroll
        for (int nt = 0; nt < 8; nt++)
            Op[row * D_MODEL + h * HDIM + nt * 16 + r15] = (__bf16)(oacc[nt][r] * inv);
    }
}

// ---------------------------------------------------------------------------
extern "C" void kernel_launch(void* const* d_in, const int* in_sizes, int n_in,
                              void* d_out, int out_size, void* d_ws, size_t ws_size,
                              hipStream_t stream) {
    (void)in_sizes; (void)n_in; (void)out_size; (void)ws_size;
    const float* hidden = (const float*)d_in[0];
    const float* cosb   = (const float*)d_in[1];
    const float* sinb   = (const float*)d_in[2];
    const float* Wq     = (const float*)d_in[3];
    const float* Wk     = (const float*)d_in[4];
    const float* Wv     = (const float*)d_in[5];
    const float* Wo     = (const float*)d_in[6];
    const float* cwq    = (const float*)d_in[7];
    const float* cwk    = (const float*)d_in[8];
    const float* cwv    = (const float*)d_in[9];
    const float* qnw    = (const float*)d_in[10];
    const float* knw    = (const float*)d_in[11];

    const size_t NEL = (size_t)T_SEQ * D_MODEL;
    __bf16* ws = (__bf16*)d_ws;
    __bf16* h_bf   = ws + 0 * NEL;   // later reused as attn_b
    __bf16* Wq_bf  = ws + 1 * NEL;   // later reused as q_proc
    __bf16* Wk_bf  = ws + 2 * NEL;   // later reused as k_proc
    __bf16* Wv_bf  = ws + 3 * NEL;   // later reused as v_t
    __bf16* Wo_bf  = ws + 4 * NEL;   // persists to final GEMM
    __bf16* q_raw  = ws + 5 * NEL;
    __bf16* k_raw  = ws + 6 * NEL;
    __bf16* v_raw  = ws + 7 * NEL;
    __bf16* q_proc = Wq_bf;
    __bf16* k_proc = Wk_bf;
    __bf16* v_t    = Wv_bf;
    __bf16* attn_b = h_bf;
    float*  out    = (float*)d_out;

    // 0. cast fp32 inputs to bf16
    cast_kernel<<<dim3(T_SEQ, 5), 256, 0, stream>>>(hidden, Wq, Wk, Wv, Wo,
                                                    h_bf, Wq_bf, Wk_bf, Wv_bf, Wo_bf);
    // 1. q,k,v = hidden @ {Wq,Wk,Wv}^T (batched)
    gemm_bt_kernel<<<dim3(16, 16, 3), 256, 0, stream>>>(
        h_bf, Wq_bf, Wk_bf, Wv_bf, q_raw, k_raw, v_raw);
    // 2. preproc: q/k (conv+silu+rms+rope) and v (conv+silu, transposed store)
    preproc_qk_kernel<<<dim3(T_SEQ, 2), 256, 0, stream>>>(
        q_raw, k_raw, cwq, cwk, qnw, knw, cosb, sinb, q_proc, k_proc);
    preproc_v_kernel<<<dim3(T_SEQ / 8, NH), 128, 0, stream>>>(v_raw, cwv, v_t);
    // 3. causal flash attention
    attn_kernel<<<dim3(T_SEQ / 64, NH), 256, 0, stream>>>(q_proc, k_proc, v_t, attn_b);
    // 4. out = attn @ Wo^T, split-K x2 with fp32 atomic epilogue
    hipMemsetAsync(d_out, 0, NEL * sizeof(float), stream);
    gemm_bt_splitk_kernel<<<dim3(16, 16, 2), 256, 0, stream>>>(attn_b, Wo_bf, out);
}